// Round 3
// baseline (313.323 us; speedup 1.0000x reference)
//
#include <hip/hip_runtime.h>

// SSIM (32,3,512,512) fp32, crop 4, 11x11 Gaussian sigma=1.5, per-batch mean.
//
// V3: vertical-first separable conv, bank-conflict-free LDS, 8px/thread stage B.
//  Stage A: vertical 11-tap of 5 moment fields (r, d, r2, d2, rd) from GLOBAL
//           (coalesced float4 rows, 2 rows x 4 cols per task) -> LDS vs[5][32][84].
//           VSW=84: row stride 336 B => wave's b128 reads tile all 32 banks
//           (VSW=80 gave 4-way conflicts: rows 2 apart were bank-identical).
//  Stage B: horizontal 11-tap, 8 cols x 1 row per thread: 5 fields x 5
//           ds_read_b128 per thread => 25 b128 per 8 outputs (was 40 per 8).
//           SSIM formula, block partial -> unique d_ws slot (no atomics).

#define IMG   512
#define OUTD  494
#define CB    4
#define TW    64
#define TH    32
#define VSW   84           // padded LDS row width (76 used); 84*4=336 B stride
#define C1F   6.5025f
#define C2F   58.5225f
#define NPIX  732108.0f    // 3*494*494
#define XBLK  8
#define YBLK  16
#define SLOTS 384          // XBLK*YBLK*3 partials per batch

__global__ __launch_bounds__(256) void ssim_main(
        const float* __restrict__ raw, const float* __restrict__ dst,
        float* __restrict__ partial) {
    __shared__ float vs[5][TH][VSW];   // 53.76 KB -> 54272 B alloc, 3 blocks/CU
    __shared__ float red[4];

    const int tid = threadIdx.x;
    const int bc  = blockIdx.z;
    const int b   = bc / 3;
    const int c3  = bc - b * 3;
    const int ty0 = blockIdx.y * TH;
    const int tx0 = blockIdx.x * TW;

    // Gaussian weights: g = exp(-x^2/(2*1.5^2)); g /= sum(g)  (matches jnp)
    float gw[11];
    {
        float s = 0.f;
        #pragma unroll
        for (int k = 0; k < 11; ++k) {
            float x = (float)(k - 5);
            gw[k] = expf(-x * x * (1.0f / 4.5f));
            s += gw[k];
        }
        float inv = 1.0f / s;
        #pragma unroll
        for (int k = 0; k < 11; ++k) gw[k] *= inv;
    }

    const float* rb = raw + (size_t)bc * (IMG * IMG);
    const float* db = dst + (size_t)bc * (IMG * IMG);

    // ---- Stage A: vertical conv. 304 tasks = 16 row-pairs x 19 x-groups. ----
    #pragma unroll 1
    for (int t = tid; t < 304; t += 256) {
        const int rp = t / 19;
        const int xg = t - rp * 19;
        int col0 = CB + tx0 + xg * 4;
        if (col0 > IMG - 4) col0 = IMG - 4;    // edge blocks: garbage cols unused
        const int row0 = CB + ty0 + rp * 2;

        float a0[5][4] = {{0.f}};   // moments for vs-row rp*2
        float a1[5][4] = {{0.f}};   // moments for vs-row rp*2+1
        #pragma unroll
        for (int k = 0; k < 12; ++k) {
            int r = row0 + k;
            if (r > IMG - 1) r = IMG - 1;      // bottom edge: rows unused
            const float4 va = *(const float4*)(rb + (size_t)r * IMG + col0);
            const float4 vc = *(const float4*)(db + (size_t)r * IMG + col0);
            const float A[4]  = {va.x, va.y, va.z, va.w};
            const float Cv[4] = {vc.x, vc.y, vc.z, vc.w};
            float p2[4], q2[4], pq[4];
            #pragma unroll
            for (int c = 0; c < 4; ++c) {
                p2[c] = A[c] * A[c];
                q2[c] = Cv[c] * Cv[c];
                pq[c] = A[c] * Cv[c];
            }
            if (k < 11) {
                const float w = gw[k];
                #pragma unroll
                for (int c = 0; c < 4; ++c) {
                    a0[0][c] = fmaf(w, A[c],  a0[0][c]);
                    a0[1][c] = fmaf(w, Cv[c], a0[1][c]);
                    a0[2][c] = fmaf(w, p2[c], a0[2][c]);
                    a0[3][c] = fmaf(w, q2[c], a0[3][c]);
                    a0[4][c] = fmaf(w, pq[c], a0[4][c]);
                }
            }
            if (k >= 1) {
                const float w = gw[k - 1];
                #pragma unroll
                for (int c = 0; c < 4; ++c) {
                    a1[0][c] = fmaf(w, A[c],  a1[0][c]);
                    a1[1][c] = fmaf(w, Cv[c], a1[1][c]);
                    a1[2][c] = fmaf(w, p2[c], a1[2][c]);
                    a1[3][c] = fmaf(w, q2[c], a1[3][c]);
                    a1[4][c] = fmaf(w, pq[c], a1[4][c]);
                }
            }
        }
        #pragma unroll
        for (int f = 0; f < 5; ++f) {
            *(float4*)&vs[f][rp * 2 + 0][xg * 4] =
                make_float4(a0[f][0], a0[f][1], a0[f][2], a0[f][3]);
            *(float4*)&vs[f][rp * 2 + 1][xg * 4] =
                make_float4(a1[f][0], a1[f][1], a1[f][2], a1[f][3]);
        }
    }
    __syncthreads();

    // ---- Stage B: horizontal conv + SSIM. Thread = 8 cols x 1 row. ----
    const int xg  = tid & 7;        // col group of 8
    const int row = tid >> 3;       // 0..31
    const int ox0 = tx0 + xg * 8;
    const int oy  = ty0 + row;
    float m[5][8];
    #pragma unroll
    for (int f = 0; f < 5; ++f) {
        const float4* vp = (const float4*)&vs[f][row][xg * 8];
        const float4 q0 = vp[0], q1 = vp[1], q2 = vp[2], q3 = vp[3], q4 = vp[4];
        const float win[20] = {q0.x, q0.y, q0.z, q0.w, q1.x, q1.y, q1.z, q1.w,
                               q2.x, q2.y, q2.z, q2.w, q3.x, q3.y, q3.z, q3.w,
                               q4.x, q4.y, q4.z, q4.w};
        #pragma unroll
        for (int c = 0; c < 8; ++c) {
            float o = 0.f;
            #pragma unroll
            for (int k = 0; k < 11; ++k) o = fmaf(gw[k], win[c + k], o);
            m[f][c] = o;
        }
    }
    float ssum = 0.f;
    if (oy < OUTD) {
        #pragma unroll
        for (int c = 0; c < 8; ++c) {
            if (ox0 + c < OUTD) {
                const float mr  = m[0][c] * 255.0f;
                const float md  = m[1][c] * 255.0f;
                const float mrr = m[2][c] * 65025.0f;
                const float mdd = m[3][c] * 65025.0f;
                const float mrd = m[4][c] * 65025.0f;
                const float mr2 = mr * mr, md2 = md * md, mpr = mr * md;
                const float num = (2.0f * mpr + C1F) * (2.0f * (mrd - mpr) + C2F);
                const float den = (mr2 + md2 + C1F) * ((mrr - mr2) + (mdd - md2) + C2F);
                ssum += num / den;
            }
        }
    }

    // block reduction -> unique partial slot (no atomics)
    #pragma unroll
    for (int off = 32; off > 0; off >>= 1)
        ssum += __shfl_down(ssum, off, 64);
    const int lane = tid & 63, wv = tid >> 6;
    if (lane == 0) red[wv] = ssum;
    __syncthreads();
    if (tid == 0) {
        const float t = red[0] + red[1] + red[2] + red[3];
        partial[(size_t)b * SLOTS + (blockIdx.y * gridDim.x + blockIdx.x) * 3 + c3] = t;
    }
}

__global__ __launch_bounds__(128) void ssim_final(
        const float* __restrict__ partial, float* __restrict__ out) {
    __shared__ float red[2];
    const int b = blockIdx.x, tid = threadIdx.x;
    float s = 0.f;
    for (int i = tid; i < SLOTS; i += 128) s += partial[(size_t)b * SLOTS + i];
    #pragma unroll
    for (int off = 32; off > 0; off >>= 1) s += __shfl_down(s, off, 64);
    if ((tid & 63) == 0) red[tid >> 6] = s;
    __syncthreads();
    if (tid == 0) out[b] = (red[0] + red[1]) * (1.0f / NPIX);
}

extern "C" void kernel_launch(void* const* d_in, const int* in_sizes, int n_in,
                              void* d_out, int out_size, void* d_ws, size_t ws_size,
                              hipStream_t stream) {
    const float* raw = (const float*)d_in[0];
    const float* dst = (const float*)d_in[1];
    float* out     = (float*)d_out;
    float* partial = (float*)d_ws;   // 32*384 fp32, fully overwritten each call

    dim3 grid(XBLK, YBLK, 96);       // 8 x 16 x (32 batches * 3 channels)
    ssim_main<<<grid, 256, 0, stream>>>(raw, dst, partial);
    ssim_final<<<32, 128, 0, stream>>>(partial, out);
}

// Round 4
// 290.043 us; speedup vs baseline: 1.0803x; 1.0803x over previous
//
#include <hip/hip_runtime.h>

// SSIM (32,3,512,512) fp32, crop 4, 11x11 Gaussian sigma=1.5, per-batch mean.
//
// V4 = V2 structure (empirically best mapping) + op-count cuts:
//  - 4 conv fields {r, d, r^2+d^2, r*d} instead of 5 (vr+vd only needed summed)
//  - 255-scaling folded into weights (gw for means in pass 1, gw255 elsewhere)
//  - v_rcp_f32 + 1 Newton iteration instead of IEEE divide
//  - row clamp hoisted out of stage A k-loop (affine addressing)
//  Stage A: vertical 11-tap from GLOBAL (coalesced float4), 2 rows x 4 cols
//           per task -> LDS vs[4][32][84]  (43 KB, 3 blocks/CU).
//  Stage B: horizontal 11-tap, 4 cols x 2 rows per thread via ds_read_b128,
//           SSIM formula, block partial -> unique d_ws slot (no atomics).
// NOTE: SQ_LDS_BANK_CONFLICT ~1e7 here is inherent b128 multi-cycle (8 clk
// per wave64 b128), not fixable aliasing — access pattern is bank-uniform.

#define IMG   512
#define OUTD  494
#define CB    4
#define TW    64
#define TH    32
#define VSW   84           // row stride 336 B: rows 0,2,4,6 hit distinct banks
#define C1F   6.5025f
#define C2F   58.5225f
#define NPIX  732108.0f    // 3*494*494
#define XBLK  8
#define YBLK  16
#define SLOTS 384

__global__ __launch_bounds__(256) void ssim_main(
        const float* __restrict__ raw, const float* __restrict__ dst,
        float* __restrict__ partial) {
    __shared__ float vs[4][TH][VSW];   // 43008 B -> 3 blocks/CU
    __shared__ float red[4];

    const int tid = threadIdx.x;
    const int bc  = blockIdx.z;
    const int b   = bc / 3;
    const int c3  = bc - b * 3;
    const int ty0 = blockIdx.y * TH;
    const int tx0 = blockIdx.x * TW;

    // Gaussian weights: g = exp(-x^2/(2*1.5^2)); g /= sum(g)  (matches jnp)
    float gw[11], gw255[11];
    {
        float s = 0.f;
        #pragma unroll
        for (int k = 0; k < 11; ++k) {
            float x = (float)(k - 5);
            gw[k] = expf(-x * x * (1.0f / 4.5f));
            s += gw[k];
        }
        float inv = 1.0f / s;
        #pragma unroll
        for (int k = 0; k < 11; ++k) { gw[k] *= inv; gw255[k] = gw[k] * 255.0f; }
    }

    const float* rb = raw + (size_t)bc * (IMG * IMG);
    const float* db = dst + (size_t)bc * (IMG * IMG);

    // ---- Stage A: vertical conv. 304 tasks = 16 row-pairs x 19 x-groups. ----
    #pragma unroll 1
    for (int t = tid; t < 304; t += 256) {
        const int rp = t / 19;
        const int xg = t - rp * 19;
        int col0 = CB + tx0 + xg * 4;
        if (col0 > IMG - 4) col0 = IMG - 4;      // edge blocks: garbage cols unused
        int row0 = CB + ty0 + rp * 2;
        if (row0 > IMG - 12) row0 = IMG - 12;    // hoisted clamp: garbage rows unused

        float a0[4][4] = {{0.f}};   // fields {r, d, r2+d2, rd} for vs-row rp*2
        float a1[4][4] = {{0.f}};   // and rp*2+1
        const float* rrow = rb + (size_t)row0 * IMG + col0;
        const float* drow = db + (size_t)row0 * IMG + col0;
        #pragma unroll
        for (int k = 0; k < 12; ++k) {
            const float4 va = *(const float4*)(rrow); rrow += IMG;
            const float4 vc = *(const float4*)(drow); drow += IMG;
            const float A[4]  = {va.x, va.y, va.z, va.w};
            const float Cv[4] = {vc.x, vc.y, vc.z, vc.w};
            float s2[4], pq[4];
            #pragma unroll
            for (int c = 0; c < 4; ++c) {
                s2[c] = fmaf(A[c], A[c], Cv[c] * Cv[c]);
                pq[c] = A[c] * Cv[c];
            }
            if (k < 11) {
                const float w = gw[k], w2 = gw255[k];
                #pragma unroll
                for (int c = 0; c < 4; ++c) {
                    a0[0][c] = fmaf(w,  A[c],  a0[0][c]);
                    a0[1][c] = fmaf(w,  Cv[c], a0[1][c]);
                    a0[2][c] = fmaf(w2, s2[c], a0[2][c]);
                    a0[3][c] = fmaf(w2, pq[c], a0[3][c]);
                }
            }
            if (k >= 1) {
                const float w = gw[k - 1], w2 = gw255[k - 1];
                #pragma unroll
                for (int c = 0; c < 4; ++c) {
                    a1[0][c] = fmaf(w,  A[c],  a1[0][c]);
                    a1[1][c] = fmaf(w,  Cv[c], a1[1][c]);
                    a1[2][c] = fmaf(w2, s2[c], a1[2][c]);
                    a1[3][c] = fmaf(w2, pq[c], a1[3][c]);
                }
            }
        }
        #pragma unroll
        for (int f = 0; f < 4; ++f) {
            *(float4*)&vs[f][rp * 2 + 0][xg * 4] =
                make_float4(a0[f][0], a0[f][1], a0[f][2], a0[f][3]);
            *(float4*)&vs[f][rp * 2 + 1][xg * 4] =
                make_float4(a1[f][0], a1[f][1], a1[f][2], a1[f][3]);
        }
    }
    __syncthreads();

    // ---- Stage B: horizontal conv + SSIM. Thread = 4 cols x 2 rows. ----
    const int xg  = tid & 15;
    const int yt  = tid >> 4;
    const int ox0 = tx0 + xg * 4;
    float ssum = 0.f;
    #pragma unroll
    for (int r2 = 0; r2 < 2; ++r2) {
        const int row = yt * 2 + r2;
        const int oy  = ty0 + row;
        float m[4][4];
        #pragma unroll
        for (int f = 0; f < 4; ++f) {
            const float4* vp = (const float4*)&vs[f][row][xg * 4];
            const float4 A = vp[0], B = vp[1], Cq = vp[2], D = vp[3];
            const float win[16] = {A.x, A.y, A.z, A.w, B.x, B.y, B.z, B.w,
                                   Cq.x, Cq.y, Cq.z, Cq.w, D.x, D.y, D.z, D.w};
            #pragma unroll
            for (int c = 0; c < 4; ++c) {
                float o = 0.f;
                #pragma unroll
                for (int k = 0; k < 11; ++k) o = fmaf(gw255[k], win[c + k], o);
                m[f][c] = o;
            }
        }
        if (oy < OUTD) {
            #pragma unroll
            for (int c = 0; c < 4; ++c) {
                if (ox0 + c < OUTD) {
                    const float mr = m[0][c], md = m[1][c];
                    const float ms = m[2][c], mp = m[3][c];
                    const float mr2 = mr * mr, md2 = md * md, mpr = mr * md;
                    const float s12 = mr2 + md2;
                    const float num = fmaf(2.0f, mpr, C1F) * fmaf(2.0f, mp - mpr, C2F);
                    const float den = (s12 + C1F) * ((ms - s12) + C2F);
                    float r = __builtin_amdgcn_rcpf(den);
                    r = r * fmaf(-den, r, 2.0f);      // 1 Newton step
                    ssum += num * r;
                }
            }
        }
    }

    // block reduction -> unique partial slot (no atomics)
    #pragma unroll
    for (int off = 32; off > 0; off >>= 1)
        ssum += __shfl_down(ssum, off, 64);
    const int lane = tid & 63, wv = tid >> 6;
    if (lane == 0) red[wv] = ssum;
    __syncthreads();
    if (tid == 0) {
        const float t = red[0] + red[1] + red[2] + red[3];
        partial[(size_t)b * SLOTS + (blockIdx.y * gridDim.x + blockIdx.x) * 3 + c3] = t;
    }
}

__global__ __launch_bounds__(128) void ssim_final(
        const float* __restrict__ partial, float* __restrict__ out) {
    __shared__ float red[2];
    const int b = blockIdx.x, tid = threadIdx.x;
    float s = 0.f;
    for (int i = tid; i < SLOTS; i += 128) s += partial[(size_t)b * SLOTS + i];
    #pragma unroll
    for (int off = 32; off > 0; off >>= 1) s += __shfl_down(s, off, 64);
    if ((tid & 63) == 0) red[tid >> 6] = s;
    __syncthreads();
    if (tid == 0) out[b] = (red[0] + red[1]) * (1.0f / NPIX);
}

extern "C" void kernel_launch(void* const* d_in, const int* in_sizes, int n_in,
                              void* d_out, int out_size, void* d_ws, size_t ws_size,
                              hipStream_t stream) {
    const float* raw = (const float*)d_in[0];
    const float* dst = (const float*)d_in[1];
    float* out     = (float*)d_out;
    float* partial = (float*)d_ws;   // 32*384 fp32, fully overwritten each call

    dim3 grid(XBLK, YBLK, 96);       // 8 x 16 x (32 batches * 3 channels)
    ssim_main<<<grid, 256, 0, stream>>>(raw, dst, partial);
    ssim_final<<<32, 128, 0, stream>>>(partial, out);
}